// Round 12
// baseline (106.304 us; speedup 1.0000x reference)
//
#include <hip/hip_runtime.h>
#include <hip/hip_bf16.h>

#define TASKS 16
#define DIM 1024
#define HID 128
#define NCLS 10
#define NB 65536
#define BM 128
#define NTILES (NB / BM + TASKS) // 528 = 8 * 66

// ws layout (ints):
//  [0, 4096)            per-block histogram partials [256 blk][16 task]
//  [4096, 4112)         per-task totals
//  [4160, 4160+NB)      rowIdx grouped by task
//  [69696, ...) shorts: W1s [T][32 kstep][8KB tile: [4 kslot][128 col][16B]] (4MB),
//                       then W2t [T][16][128]
#define WS_TOT  4096
#define WS_RIDX 4160
#define WS_W1S  (WS_RIDX + NB)

typedef __attribute__((ext_vector_type(8))) short bf16x8;
typedef __attribute__((ext_vector_type(4))) float f32x4;

__device__ __forceinline__ unsigned short f2bf(float f) {
    union { __hip_bfloat16 h; unsigned short s; } u; u.h = __float2bfloat16(f); return u.s;
}
__device__ __forceinline__ bf16x8 pack8(f32x4 a, f32x4 b) {
    bf16x8 r;
    r[0]=(short)f2bf(a[0]); r[1]=(short)f2bf(a[1]); r[2]=(short)f2bf(a[2]); r[3]=(short)f2bf(a[3]);
    r[4]=(short)f2bf(b[0]); r[5]=(short)f2bf(b[1]); r[6]=(short)f2bf(b[2]); r[7]=(short)f2bf(b[3]);
    return r;
}

__device__ __forceinline__ void glds16(const void* gsrc, void* ldst) {
    __builtin_amdgcn_global_load_lds(
        (const __attribute__((address_space(1))) unsigned*)gsrc,
        (__attribute__((address_space(3))) unsigned*)ldst, 16, 0, 0);
}

// ---- pass 1: histogram partials + W1 -> kslot-major bf16 tiles + W2 transpose ----
__global__ __launch_bounds__(256) void k_pre(const int* __restrict__ tid_arr,
                                             const float* __restrict__ W1,
                                             const float* __restrict__ W2,
                                             int* __restrict__ ws) {
    const int blk = blockIdx.x, tid = threadIdx.x;
    if (blk < 256) {
        __shared__ int l[TASKS];
        if (tid < TASKS) l[tid] = 0;
        __syncthreads();
        atomicAdd(&l[tid_arr[blk * 256 + tid]], 1);
        __syncthreads();
        if (tid < TASKS) ws[blk * TASKS + tid] = l[tid];
    } else if (blk < 768) {
        // 8KB tile per (t,kt): [kslot 4][col 128][16B]; k = kt*32 + kslot*8 + j
        const int idx = blk - 256;
        const int t = idx >> 5, kt = idx & 31;
        __shared__ float ld[32 * 132];
        const float* src = W1 + ((size_t)t * DIM + kt * 32) * HID;
        #pragma unroll
        for (int r = 0; r < 16; ++r) {
            const int fl = r * 256 + tid;
            ld[(fl >> 7) * 132 + (fl & 127)] = src[fl];
        }
        __syncthreads();
        char* dst = (char*)((short*)(ws + WS_W1S) + ((size_t)(t * 32 + kt) << 12));
        #pragma unroll
        for (int g = 0; g < 2; ++g) {
            const int p = tid * 32 + g * 16;
            const int kslot = p >> 11, col = (p >> 4) & 127;
            bf16x8 v;
            #pragma unroll
            for (int j = 0; j < 8; ++j)
                v[j] = (short)f2bf(ld[(kslot * 8 + j) * 132 + col]);
            *(bf16x8*)(dst + p) = v;
        }
    } else {
        const int t = blk - 768;
        short* W2t = (short*)(ws + WS_W1S) + ((size_t)TASKS * 32 * 4096);
        #pragma unroll
        for (int i = 0; i < 8; ++i) {
            const int o = i * 256 + tid, c = o >> 7, h = o & 127;
            const float v = (c < NCLS) ? W2[((size_t)t * HID + h) * NCLS + c] : 0.f;
            W2t[((size_t)t * 16 + c) * HID + h] = (short)f2bf(v);
        }
    }
}

// ---- pass 2: deterministic scatter, parallel 2-level prefix ----
__global__ __launch_bounds__(256) void k_scatter(const int* __restrict__ tid_arr,
                                                 int* __restrict__ ws) {
    __shared__ int part[256 * TASKS];
    __shared__ int sums[16 * TASKS];
    __shared__ int l[TASKS], offl[TASKS], prel[TASKS], totl[TASKS];
    const int b = blockIdx.x, tid = threadIdx.x;
    #pragma unroll
    for (int r = 0; r < 16; ++r) part[r * 256 + tid] = ws[r * 256 + tid];
    if (tid < TASKS) l[tid] = 0;
    __syncthreads();
    const int t = tid_arr[b * 256 + tid];
    const int rank = atomicAdd(&l[t], 1);
    {
        const int c = tid >> 4, tt = tid & 15;
        int s = 0;
        #pragma unroll
        for (int bb = 0; bb < 16; ++bb) s += part[(c * 16 + bb) * TASKS + tt];
        sums[c * TASKS + tt] = s;
    }
    __syncthreads();
    if (tid < TASKS) {
        const int cb = b >> 4;
        int pre = 0;
        for (int c = 0; c < cb; ++c) pre += sums[c * TASKS + tid];
        for (int bb = cb * 16; bb < b; ++bb) pre += part[bb * TASKS + tid];
        int tot = 0;
        #pragma unroll
        for (int c = 0; c < 16; ++c) tot += sums[c * TASKS + tid];
        prel[tid] = pre; totl[tid] = tot;
        if (b == 0) ws[WS_TOT + tid] = tot;
    }
    __syncthreads();
    if (tid == 0) {
        int ro = 0;
        for (int k = 0; k < TASKS; ++k) { offl[k] = ro; ro += totl[k]; }
    }
    __syncthreads();
    ws[WS_RIDX + offl[t] + prel[t] + rank] = b * 256 + tid;
}

// ---- pass 3: fused grouped GEMM; A f32 + B bf16 both via glds, 3-buf ring ----
__global__ __launch_bounds__(512, 4) void k_main(
    const float* __restrict__ x, const float* __restrict__ b1,
    const float* __restrict__ b2, const int* __restrict__ ws,
    float* __restrict__ out)
{
    // buf stride 24KB: A f32 [16 grp][8 chunk][8 row][16B] (16KB) | B bf16 [4 ks][128 col][16B] (8KB)
    // 3 bufs = 72KB; epilogue reuses base as hl[128][256B] (32KB)
    __shared__ __align__(16) char smem[73728];
    __shared__ int ridx[BM];

    const int* tot = ws + WS_TOT;
    const int* rowIdx = ws + WS_RIDX;
    const short* W1s = (const short*)(ws + WS_W1S);
    const short* W2t = W1s + ((size_t)TASKS * 32 * 4096);

    const int w = (blockIdx.x & 7) * (NTILES / 8) + (blockIdx.x >> 3);

    int t = -1, m = 0, gstart = 0;
    {
        int accT = 0, accO = 0;
        for (int k = 0; k < TASKS; ++k) {
            const int c = tot[k], nt = (c + BM - 1) >> 7;
            if (t < 0 && w < accT + nt) {
                t = k; gstart = accO + (w - accT) * BM;
                m = c - (w - accT) * BM; if (m > BM) m = BM;
            }
            accT += nt; accO += c;
        }
    }
    if (t < 0) return;

    const int tid = threadIdx.x;
    if (tid < BM) ridx[tid] = rowIdx[gstart + (tid < m ? tid : m - 1)];
    __syncthreads();

    const int lane = tid & 63, wv = tid >> 6;          // 8 waves
    const int lg = lane >> 4, lr = lane & 15;
    const int wrow = (wv & 1) * 64, wcol = (wv >> 1) * 32;

    // A staging: lane l = (chunk<<3)|ro; glds instr i covers rows 8i..8i+7,
    // LDS(row,chunk) = grp(row>>3)*1024 + chunk*128 + (row&7)*16  (matches lane*16)
    const int ro = lane & 7, ch = lane >> 3;
    const int rowA0 = wv * 16 + ro;                    // instr 2wv
    const int rowA1 = rowA0 + 8;                       // instr 2wv+1
    const float* srcA0 = x + ((size_t)ridx[rowA0] << 10) + ch * 4;
    const float* srcA1 = x + ((size_t)ridx[rowA1] << 10) + ch * 4;
    const char* w1sT = (const char*)W1s + ((size_t)t << 18);

    f32x4 acc[4][2] = {};

    auto ISSUE = [&](int bufIdx, int KT) {
        char* bufb = smem + bufIdx * 24576;
        glds16(srcA0 + KT * 32, bufb + (2 * wv) * 1024);
        glds16(srcA1 + KT * 32, bufb + (2 * wv + 1) * 1024);
        glds16(w1sT + ((size_t)KT << 13) + wv * 1024 + lane * 16,
               bufb + 16384 + wv * 1024);
    };
    auto COMPUTE = [&](int bufIdx) {
        const char* ab = smem + bufIdx * 24576;
        const char* bb = ab + 16384;
        bf16x8 af[4], bfr[2];
        #pragma unroll
        for (int rf = 0; rf < 4; ++rf) {
            const int row = wrow + rf * 16 + lr;
            const char* p = ab + ((row >> 3) << 10) + lg * 256 + ((row & 7) << 4);
            f32x4 a0 = *(const f32x4*)p;
            f32x4 a1 = *(const f32x4*)(p + 128);
            af[rf] = pack8(a0, a1);
        }
        #pragma unroll
        for (int cf = 0; cf < 2; ++cf)
            bfr[cf] = *(const bf16x8*)(bb + lg * 2048 + ((wcol + cf * 16 + lr) << 4));
        #pragma unroll
        for (int rf = 0; rf < 4; ++rf)
            #pragma unroll
            for (int cf = 0; cf < 2; ++cf)
                acc[rf][cf] = __builtin_amdgcn_mfma_f32_16x16x32_bf16(af[rf], bfr[cf], acc[rf][cf], 0, 0, 0);
    };
    auto BODY = [&](int kt, int bc, int bn) {
        ISSUE(bn, kt + 2 < 32 ? kt + 2 : 31);          // junk tail goes to never-read buf
        COMPUTE(bc);
        asm volatile("s_waitcnt vmcnt(3)" ::: "memory");   // drain tile kt+1 (3 glds/wave)
        __builtin_amdgcn_s_barrier();
        __builtin_amdgcn_sched_barrier(0);
    };

    // prologue: tiles 0,1 in flight; wait tile 0 (leave tile 1's 3)
    ISSUE(0, 0);
    ISSUE(1, 1);
    asm volatile("s_waitcnt vmcnt(3)" ::: "memory");
    __builtin_amdgcn_s_barrier();
    __builtin_amdgcn_sched_barrier(0);

    for (int k3 = 0; k3 < 30; k3 += 3) {
        BODY(k3 + 0, 0, 2);
        BODY(k3 + 1, 1, 0);
        BODY(k3 + 2, 2, 1);
    }
    BODY(30, 0, 2);
    BODY(31, 1, 0);
    __syncthreads();   // full drain (junk tail glds) before LDS reuse

    // epilogue: bias + relu -> hl[128][256B] swizzled (reuses smem base)
    char* hl = smem;
    #pragma unroll
    for (int cf = 0; cf < 2; ++cf) {
        const int col = wcol + cf * 16 + lr;
        const float b1v = b1[t * HID + col];
        #pragma unroll
        for (int rf = 0; rf < 4; ++rf)
            #pragma unroll
            for (int q = 0; q < 4; ++q) {
                const int row = wrow + rf * 16 + lg * 4 + q;
                const float hv = fmaxf(acc[rf][cf][q] + b1v, 0.f);
                *(unsigned short*)(hl + row * 256 +
                    (((col >> 3) ^ (row & 7)) << 4) + (col & 7) * 2) = f2bf(hv);
            }
    }
    __syncthreads();

    // GEMM2: [128 x 128] * [128 x 16]; wave wv owns rows wv*16..+15
    const int row2 = wv * 16 + lr;
    f32x4 acc2 = {};
    #pragma unroll
    for (int ks = 0; ks < 4; ++ks) {
        bf16x8 bvv = *(const bf16x8*)(W2t + (((size_t)t * 16 + lr) << 7) + ks * 32 + lg * 8);
        bf16x8 avv = *(const bf16x8*)(hl + row2 * 256 + (((ks * 4 + lg) ^ (row2 & 7)) << 4));
        acc2 = __builtin_amdgcn_mfma_f32_16x16x32_bf16(avv, bvv, acc2, 0, 0, 0);
    }
    if (lr < NCLS) {
        const float b2v = b2[t * NCLS + lr];
        #pragma unroll
        for (int q = 0; q < 4; ++q) {
            const int row = wv * 16 + lg * 4 + q;
            if (row < m) out[(size_t)ridx[row] * NCLS + lr] = acc2[q] + b2v;
        }
    }
}

extern "C" void kernel_launch(void* const* d_in, const int* in_sizes, int n_in,
                              void* d_out, int out_size, void* d_ws, size_t ws_size,
                              hipStream_t stream) {
    (void)in_sizes; (void)n_in; (void)out_size; (void)ws_size;
    const float* x       = (const float*)d_in[0];
    const int*   task_id = (const int*)d_in[1];
    const float* W1      = (const float*)d_in[2];
    const float* b1      = (const float*)d_in[3];
    const float* W2      = (const float*)d_in[4];
    const float* b2      = (const float*)d_in[5];
    float* out = (float*)d_out;
    int* ws = (int*)d_ws;
    k_pre<<<784, 256, 0, stream>>>(task_id, W1, W2, ws);
    k_scatter<<<256, 256, 0, stream>>>(task_id, ws);
    k_main<<<NTILES, 512, 0, stream>>>(x, b1, b2, ws, out);
}

// Round 13
// 84.875 us; speedup vs baseline: 1.2525x; 1.2525x over previous
//
#include <hip/hip_runtime.h>
#include <hip/hip_bf16.h>

#define TASKS 16
#define DIM 1024
#define HID 128
#define NCLS 10
#define NB 65536
#define BM 128
#define NTILES (NB / BM + TASKS) // 528 = 8 * 66

// ws layout (ints):
//  [0, 4096)            per-block histogram partials [256 blk][16 task]
//  [4096, 4112)         per-task totals
//  [4160, 4160+NB)      rowIdx grouped by task
//  [69696, ...) shorts: W1s [T][32 kstep][8KB tile: [4 kslot][128 col][16B]] (4MB),
//                       then W2t [T][16][128]
#define WS_TOT  4096
#define WS_RIDX 4160
#define WS_W1S  (WS_RIDX + NB)

typedef __attribute__((ext_vector_type(8))) short bf16x8;
typedef __attribute__((ext_vector_type(4))) float f32x4;

__device__ __forceinline__ unsigned short f2bf(float f) {
    union { __hip_bfloat16 h; unsigned short s; } u; u.h = __float2bfloat16(f); return u.s;
}
__device__ __forceinline__ bf16x8 pack8(f32x4 a, f32x4 b) {
    bf16x8 r;
    r[0]=(short)f2bf(a[0]); r[1]=(short)f2bf(a[1]); r[2]=(short)f2bf(a[2]); r[3]=(short)f2bf(a[3]);
    r[4]=(short)f2bf(b[0]); r[5]=(short)f2bf(b[1]); r[6]=(short)f2bf(b[2]); r[7]=(short)f2bf(b[3]);
    return r;
}

__device__ __forceinline__ void glds16(const void* gsrc, void* ldst) {
    __builtin_amdgcn_global_load_lds(
        (const __attribute__((address_space(1))) unsigned*)gsrc,
        (__attribute__((address_space(3))) unsigned*)ldst, 16, 0, 0);
}

// ---- pass 1: histogram partials + W1 -> kslot-major bf16 tiles + W2 transpose ----
__global__ __launch_bounds__(256) void k_pre(const int* __restrict__ tid_arr,
                                             const float* __restrict__ W1,
                                             const float* __restrict__ W2,
                                             int* __restrict__ ws) {
    const int blk = blockIdx.x, tid = threadIdx.x;
    if (blk < 256) {
        __shared__ int l[TASKS];
        if (tid < TASKS) l[tid] = 0;
        __syncthreads();
        atomicAdd(&l[tid_arr[blk * 256 + tid]], 1);
        __syncthreads();
        if (tid < TASKS) ws[blk * TASKS + tid] = l[tid];
    } else if (blk < 768) {
        // 8KB tile per (t,kt): [kslot 4][col 128][16B]; k = kt*32 + kslot*8 + j
        const int idx = blk - 256;
        const int t = idx >> 5, kt = idx & 31;
        __shared__ float ld[32 * 132];
        const float* src = W1 + ((size_t)t * DIM + kt * 32) * HID;
        #pragma unroll
        for (int r = 0; r < 16; ++r) {
            const int fl = r * 256 + tid;
            ld[(fl >> 7) * 132 + (fl & 127)] = src[fl];
        }
        __syncthreads();
        char* dst = (char*)((short*)(ws + WS_W1S) + ((size_t)(t * 32 + kt) << 12));
        #pragma unroll
        for (int g = 0; g < 2; ++g) {
            const int p = tid * 32 + g * 16;
            const int kslot = p >> 11, col = (p >> 4) & 127;
            bf16x8 v;
            #pragma unroll
            for (int j = 0; j < 8; ++j)
                v[j] = (short)f2bf(ld[(kslot * 8 + j) * 132 + col]);
            *(bf16x8*)(dst + p) = v;
        }
    } else {
        const int t = blk - 768;
        short* W2t = (short*)(ws + WS_W1S) + ((size_t)TASKS * 32 * 4096);
        #pragma unroll
        for (int i = 0; i < 8; ++i) {
            const int o = i * 256 + tid, c = o >> 7, h = o & 127;
            const float v = (c < NCLS) ? W2[((size_t)t * HID + h) * NCLS + c] : 0.f;
            W2t[((size_t)t * 16 + c) * HID + h] = (short)f2bf(v);
        }
    }
}

// ---- pass 2: deterministic scatter, parallel 2-level prefix ----
__global__ __launch_bounds__(256) void k_scatter(const int* __restrict__ tid_arr,
                                                 int* __restrict__ ws) {
    __shared__ int part[256 * TASKS];
    __shared__ int sums[16 * TASKS];
    __shared__ int l[TASKS], offl[TASKS], prel[TASKS], totl[TASKS];
    const int b = blockIdx.x, tid = threadIdx.x;
    #pragma unroll
    for (int r = 0; r < 16; ++r) part[r * 256 + tid] = ws[r * 256 + tid];
    if (tid < TASKS) l[tid] = 0;
    __syncthreads();
    const int t = tid_arr[b * 256 + tid];
    const int rank = atomicAdd(&l[t], 1);
    {
        const int c = tid >> 4, tt = tid & 15;
        int s = 0;
        #pragma unroll
        for (int bb = 0; bb < 16; ++bb) s += part[(c * 16 + bb) * TASKS + tt];
        sums[c * TASKS + tt] = s;
    }
    __syncthreads();
    if (tid < TASKS) {
        const int cb = b >> 4;
        int pre = 0;
        for (int c = 0; c < cb; ++c) pre += sums[c * TASKS + tid];
        for (int bb = cb * 16; bb < b; ++bb) pre += part[bb * TASKS + tid];
        int tot = 0;
        #pragma unroll
        for (int c = 0; c < 16; ++c) tot += sums[c * TASKS + tid];
        prel[tid] = pre; totl[tid] = tot;
        if (b == 0) ws[WS_TOT + tid] = tot;
    }
    __syncthreads();
    if (tid == 0) {
        int ro = 0;
        for (int k = 0; k < TASKS; ++k) { offl[k] = ro; ro += totl[k]; }
    }
    __syncthreads();
    ws[WS_RIDX + offl[t] + prel[t] + rank] = b * 256 + tid;
}

// ---- pass 3: fused grouped GEMM; A direct-to-register (per-wave rows), B glds 3-ring ----
__global__ __launch_bounds__(512, 4) void k_main(
    const float* __restrict__ x, const float* __restrict__ b1,
    const float* __restrict__ b2, const int* __restrict__ ws,
    float* __restrict__ out)
{
    // B ring: 3 x 8KB = 24KB; epilogue reuses base as hl[128][256B] (32KB)
    __shared__ __align__(16) char smem[32768];
    __shared__ int ridx[BM];

    const int* tot = ws + WS_TOT;
    const int* rowIdx = ws + WS_RIDX;
    const short* W1s = (const short*)(ws + WS_W1S);
    const short* W2t = W1s + ((size_t)TASKS * 32 * 4096);

    const int w = (blockIdx.x & 7) * (NTILES / 8) + (blockIdx.x >> 3);

    int t = -1, m = 0, gstart = 0;
    {
        int accT = 0, accO = 0;
        for (int k = 0; k < TASKS; ++k) {
            const int c = tot[k], nt = (c + BM - 1) >> 7;
            if (t < 0 && w < accT + nt) {
                t = k; gstart = accO + (w - accT) * BM;
                m = c - (w - accT) * BM; if (m > BM) m = BM;
            }
            accT += nt; accO += c;
        }
    }
    if (t < 0) return;

    const int tid = threadIdx.x;
    if (tid < BM) ridx[tid] = rowIdx[gstart + (tid < m ? tid : m - 1)];
    __syncthreads();

    const int lane = tid & 63, wv = tid >> 6;          // 8 waves, wave owns rows wv*16..+15
    const int lg = lane >> 4, lr = lane & 15;

    // A: lane (lg,lr) owns exactly its MFMA fragment: x[ridx[wv*16+lr]][kt*32 + lg*8 .. +7]
    const float* srcA = x + ((size_t)ridx[wv * 16 + lr] << 10) + lg * 8;
    const char* w1sT = (const char*)W1s + ((size_t)t << 18);

    f32x4 aS[3][2];            // 3-slot A prefetch ring (fully unrolled -> static)
    f32x4 acc[8] = {};

    auto LOADA = [&](int s, int kt) {
        aS[s][0] = *(const f32x4*)(srcA + kt * 32);
        aS[s][1] = *(const f32x4*)(srcA + kt * 32 + 4);
    };
    auto ISSUEB = [&](int bufIdx, int kt) {
        glds16(w1sT + ((size_t)kt << 13) + wv * 1024 + lane * 16,
               smem + bufIdx * 8192 + wv * 1024);       // dst wave-uniform
    };
    auto COMPUTE = [&](int bufIdx, int s) {
        const char* bb = smem + bufIdx * 8192;
        bf16x8 af = pack8(aS[s][0], aS[s][1]);
        bf16x8 bfr[8];
        #pragma unroll
        for (int cf = 0; cf < 8; ++cf)
            bfr[cf] = *(const bf16x8*)(bb + lg * 2048 + ((cf * 16 + lr) << 4));
        #pragma unroll
        for (int cf = 0; cf < 8; ++cf)
            acc[cf] = __builtin_amdgcn_mfma_f32_16x16x32_bf16(af, bfr[cf], acc[cf], 0, 0, 0);
    };

    // prologue: tiles 0,1 in flight; drain B0 only (vmcnt(5) leaves A0,A1,B1)
    ISSUEB(0, 0); LOADA(0, 0);
    ISSUEB(1, 1); LOADA(1, 1);
    asm volatile("s_waitcnt vmcnt(5)" ::: "memory");
    __builtin_amdgcn_s_barrier();
    __builtin_amdgcn_sched_barrier(0);

    // steady: issue B/A for kt+2; compute kt; vmcnt(3) drains B_{kt+1},A_{kt+1},
    // leaves [B_{kt+2}, A_{kt+2}] (3 ops) in flight across the barrier.
    #pragma unroll
    for (int kt = 0; kt < 32; ++kt) {
        const int kn = kt + 2 < 32 ? kt + 2 : 31;      // clamp keeps counts uniform
        ISSUEB((kt + 2) % 3, kn);
        LOADA((kt + 2) % 3, kn);
        COMPUTE(kt % 3, kt % 3);
        asm volatile("s_waitcnt vmcnt(3)" ::: "memory");
        __builtin_amdgcn_s_barrier();
        __builtin_amdgcn_sched_barrier(0);
    }
    __syncthreads();   // full drain (junk tail ops) before LDS reuse

    // epilogue: bias + relu -> hl[128][256B] swizzled (reuses smem base)
    char* hl = smem;
    #pragma unroll
    for (int cf = 0; cf < 8; ++cf) {
        const int col = cf * 16 + lr;
        const float b1v = b1[t * HID + col];
        #pragma unroll
        for (int q = 0; q < 4; ++q) {
            const int row = wv * 16 + lg * 4 + q;
            const float hv = fmaxf(acc[cf][q] + b1v, 0.f);
            *(unsigned short*)(hl + row * 256 +
                (((col >> 3) ^ (row & 7)) << 4) + (col & 7) * 2) = f2bf(hv);
        }
    }
    __syncthreads();

    // GEMM2: [128 x 128] * [128 x 16]; wave wv owns rows wv*16..+15
    const int row2 = wv * 16 + lr;
    f32x4 acc2 = {};
    #pragma unroll
    for (int ks = 0; ks < 4; ++ks) {
        bf16x8 bvv = *(const bf16x8*)(W2t + (((size_t)t * 16 + lr) << 7) + ks * 32 + lg * 8);
        bf16x8 avv = *(const bf16x8*)(hl + row2 * 256 + (((ks * 4 + lg) ^ (row2 & 7)) << 4));
        acc2 = __builtin_amdgcn_mfma_f32_16x16x32_bf16(avv, bvv, acc2, 0, 0, 0);
    }
    if (lr < NCLS) {
        const float b2v = b2[t * NCLS + lr];
        #pragma unroll
        for (int q = 0; q < 4; ++q) {
            const int row = wv * 16 + lg * 4 + q;
            if (row < m) out[(size_t)ridx[row] * NCLS + lr] = acc2[q] + b2v;
        }
    }
}

extern "C" void kernel_launch(void* const* d_in, const int* in_sizes, int n_in,
                              void* d_out, int out_size, void* d_ws, size_t ws_size,
                              hipStream_t stream) {
    (void)in_sizes; (void)n_in; (void)out_size; (void)ws_size;
    const float* x       = (const float*)d_in[0];
    const int*   task_id = (const int*)d_in[1];
    const float* W1      = (const float*)d_in[2];
    const float* b1      = (const float*)d_in[3];
    const float* W2      = (const float*)d_in[4];
    const float* b2      = (const float*)d_in[5];
    float* out = (float*)d_out;
    int* ws = (int*)d_ws;
    k_pre<<<784, 256, 0, stream>>>(task_id, W1, W2, ws);
    k_scatter<<<256, 256, 0, stream>>>(task_id, ws);
    k_main<<<NTILES, 512, 0, stream>>>(x, b1, b2, ws, out);
}

// Round 14
// 78.131 us; speedup vs baseline: 1.3606x; 1.0863x over previous
//
#include <hip/hip_runtime.h>
#include <hip/hip_bf16.h>

#define TASKS 16
#define DIM 1024
#define HID 128
#define NCLS 10
#define NB 65536
#define BM 128
#define NTILES (NB / BM + TASKS) // 528 = 8 * 66

// ws layout (ints):
//  [0, 16)                      per-task cursors (zeroed by memsetAsync; totals after k_prep)
//  [64, 64 + 16*NB)             rowIdx, per-task capacity NB: task t at [64 + t*NB, ...)
//  [64 + 16*NB, ...) shorts:    W1s [T][32 kstep][8KB tile: [4 kslot][128 col][16B]] (4MB),
//                               then W2t [T][16][128] bf16
#define WS_RIDX 64
#define WS_W1S  (WS_RIDX + 16 * NB)

typedef __attribute__((ext_vector_type(8))) short bf16x8;
typedef __attribute__((ext_vector_type(4))) float f32x4;
typedef __attribute__((ext_vector_type(2))) unsigned u32x2;

__device__ __forceinline__ unsigned short f2bf(float f) {
    union { __hip_bfloat16 h; unsigned short s; } u; u.h = __float2bfloat16(f); return u.s;
}

__device__ __forceinline__ void glds16(const void* gsrc, void* ldst) {
    __builtin_amdgcn_global_load_lds(
        (const __attribute__((address_space(1))) unsigned*)gsrc,
        (__attribute__((address_space(3))) unsigned*)ldst, 16, 0, 0);
}

// ---- pass 1 (single prep kernel): scatter (atomic-cursor) || W1 tiles || W2 ----
__global__ __launch_bounds__(256) void k_prep(const int* __restrict__ tid_arr,
                                              const float* __restrict__ W1,
                                              const float* __restrict__ W2,
                                              int* __restrict__ ws) {
    const int blk = blockIdx.x, tid = threadIdx.x;
    if (blk < 256) {
        // scatter: per-block LDS hist -> one global atomicAdd per task -> ranked write.
        // Order nondeterministic but output values/locations order-independent.
        __shared__ int l[TASKS], base[TASKS];
        if (tid < TASKS) l[tid] = 0;
        __syncthreads();
        const int i = blk * 256 + tid;
        const int t = tid_arr[i];
        const int rank = atomicAdd(&l[t], 1);
        __syncthreads();
        if (tid < TASKS && l[tid] > 0) base[tid] = atomicAdd(&ws[tid], l[tid]);
        __syncthreads();
        ws[WS_RIDX + t * NB + base[t] + rank] = i;
    } else if (blk < 768) {
        // 8KB tile per (t,kt): [kslot 4][col 128][16B]; k = kt*32 + kslot*8 + j
        const int idx = blk - 256;
        const int t = idx >> 5, kt = idx & 31;
        __shared__ float ld[32 * 132];
        const float* src = W1 + ((size_t)t * DIM + kt * 32) * HID;
        #pragma unroll
        for (int r = 0; r < 16; ++r) {
            const int fl = r * 256 + tid;
            ld[(fl >> 7) * 132 + (fl & 127)] = src[fl];
        }
        __syncthreads();
        char* dst = (char*)((short*)(ws + WS_W1S) + ((size_t)(t * 32 + kt) << 12));
        #pragma unroll
        for (int g = 0; g < 2; ++g) {
            const int p = tid * 32 + g * 16;
            const int kslot = p >> 11, col = (p >> 4) & 127;
            bf16x8 v;
            #pragma unroll
            for (int j = 0; j < 8; ++j)
                v[j] = (short)f2bf(ld[(kslot * 8 + j) * 132 + col]);
            *(bf16x8*)(dst + p) = v;
        }
    } else {
        const int t = blk - 768;
        short* W2t = (short*)(ws + WS_W1S) + ((size_t)TASKS * 32 * 4096);
        #pragma unroll
        for (int i = 0; i < 8; ++i) {
            const int o = i * 256 + tid, c = o >> 7, h = o & 127;
            const float v = (c < NCLS) ? W2[((size_t)t * HID + h) * NCLS + c] : 0.f;
            W2t[((size_t)t * 16 + c) * HID + h] = (short)f2bf(v);
        }
    }
}

// ---- pass 2: fused grouped GEMM (r10 structure, 3 blocks/CU) ----
__global__ __launch_bounds__(512, 6) void k_main(
    const float* __restrict__ x, const float* __restrict__ b1,
    const float* __restrict__ b2, const int* __restrict__ ws,
    float* __restrict__ out)
{
    // per buf: A [4 kslot][128 row][16B] = 8KB | B [4 kslot][128 col][16B] = 8KB
    // 2 bufs = 32KB; epilogue reuses as hl[128][256B]
    __shared__ __align__(16) short smem[16384];
    __shared__ int ridx[BM];

    const int* tot = ws;                       // cursors == per-task totals after k_prep
    const int* rowIdx = ws + WS_RIDX;
    const short* W1s = (const short*)(ws + WS_W1S);
    const short* W2t = W1s + ((size_t)TASKS * 32 * 4096);

    const int w = (blockIdx.x & 7) * (NTILES / 8) + (blockIdx.x >> 3);

    int t = -1, m = 0, tileInT = 0;
    {
        int accT = 0;
        for (int k = 0; k < TASKS; ++k) {
            const int c = tot[k], nt = (c + BM - 1) >> 7;
            if (t < 0 && w < accT + nt) {
                t = k; tileInT = w - accT;
                m = c - tileInT * BM; if (m > BM) m = BM;
            }
            accT += nt;
        }
    }
    if (t < 0) return;

    const int tid = threadIdx.x;
    if (tid < BM) {
        const int rr = tid < m ? tid : m - 1;
        ridx[tid] = rowIdx[t * NB + tileInT * BM + rr];
    }
    __syncthreads();

    const int lane = tid & 63, wv = tid >> 6;          // 8 waves
    const int lg = lane >> 4, lr = lane & 15;
    const int rh = wv & 1, cq = wv >> 1;               // 2 row-halves x 4 col-quarters
    const int wrow = rh * 64, wcol = cq * 32;

    // A staging: wave wv covers rows wv*16..+15; instr j: 8 rows, 8 lanes/row x 16B
    const float* gpA[2];
    unsigned wbA[2];
    #pragma unroll
    for (int j = 0; j < 2; ++j) {
        const int row = wv * 16 + j * 8 + (lane >> 3);
        gpA[j] = x + ((size_t)ridx[row] << 10) + (lane & 7) * 4;
        wbA[j] = ((unsigned)((lane & 7) >> 1)) * 2048 + row * 16 + (lane & 1) * 8;
    }
    // B staging: 1 glds/wave, source sequential in kslot-major W1s
    const char* w1sT = (const char*)W1s + ((size_t)t << 18);

    f32x4 a8[2];
    f32x4 acc[4][2] = {};

    auto LOADA = [&](int kt) {
        #pragma unroll
        for (int j = 0; j < 2; ++j) a8[j] = *(const f32x4*)(gpA[j] + kt * 32);
    };
    auto WRITEA = [&](int buf) {
        char* ab = (char*)smem + buf * 16384;
        #pragma unroll
        for (int j = 0; j < 2; ++j) {
            u32x2 pk;
            pk[0] = ((unsigned)f2bf(a8[j][1]) << 16) | (unsigned)f2bf(a8[j][0]);
            pk[1] = ((unsigned)f2bf(a8[j][3]) << 16) | (unsigned)f2bf(a8[j][2]);
            *(u32x2*)(ab + wbA[j]) = pk;               // ds_write_b64
        }
    };
    auto ISSUEB = [&](int buf, int kt) {
        const char* src = w1sT + ((size_t)kt << 13) + wv * 1024 + lane * 16;
        char* dst = (char*)smem + buf * 16384 + 8192 + wv * 1024;  // wave-uniform
        glds16(src, dst);
    };
    auto COMPUTE = [&](int buf) {
        const char* ab = (const char*)smem + buf * 16384;
        const char* bb = ab + 8192;
        bf16x8 af[4], bfr[2];
        #pragma unroll
        for (int rf = 0; rf < 4; ++rf)
            af[rf] = *(const bf16x8*)(ab + lg * 2048 + (wrow + rf * 16 + lr) * 16);
        #pragma unroll
        for (int cf = 0; cf < 2; ++cf)
            bfr[cf] = *(const bf16x8*)(bb + lg * 2048 + (wcol + cf * 16 + lr) * 16);
        #pragma unroll
        for (int rf = 0; rf < 4; ++rf)
            #pragma unroll
            for (int cf = 0; cf < 2; ++cf)
                acc[rf][cf] = __builtin_amdgcn_mfma_f32_16x16x32_bf16(af[rf], bfr[cf], acc[rf][cf], 0, 0, 0);
    };

    // prologue: in-flight at wait = [g0(1), A1(2)] -> vmcnt(2) drains g0
    LOADA(0);
    ISSUEB(0, 0);
    WRITEA(0);                 // compiler waits A0 only (older than g0)
    LOADA(1);
    asm volatile("s_waitcnt vmcnt(2) lgkmcnt(0)" ::: "memory");
    __builtin_amdgcn_s_barrier();
    __builtin_amdgcn_sched_barrier(0);

    // steady: [A_{kt+1}] -> +g_{kt+1} -> WRITEA waits A -> +A_{kt+2} -> vmcnt(2) drains g
    #pragma unroll 2
    for (int kt = 0; kt < 32; ++kt) {
        const int buf = kt & 1;
        ISSUEB(buf ^ 1, kt + 1 < 32 ? kt + 1 : 31);
        WRITEA(buf ^ 1);
        LOADA(kt + 2 < 32 ? kt + 2 : 31);
        COMPUTE(buf);
        asm volatile("s_waitcnt vmcnt(2) lgkmcnt(0)" ::: "memory");
        __builtin_amdgcn_s_barrier();
        __builtin_amdgcn_sched_barrier(0);
    }
    __syncthreads();   // full drain before LDS reuse

    // epilogue: bias + relu -> hl[128][256B] swizzled
    short* hl = smem;
    #pragma unroll
    for (int cf = 0; cf < 2; ++cf) {
        const int col = wcol + cf * 16 + lr;
        const float b1v = b1[t * HID + col];
        #pragma unroll
        for (int rf = 0; rf < 4; ++rf)
            #pragma unroll
            for (int q = 0; q < 4; ++q) {
                const int row = wrow + rf * 16 + lg * 4 + q;
                const float hv = fmaxf(acc[rf][cf][q] + b1v, 0.f);
                *(unsigned short*)((char*)hl + row * 256 +
                    (((col >> 3) ^ (row & 7)) << 4) + (col & 7) * 2) = f2bf(hv);
            }
    }
    __syncthreads();

    // GEMM2: [128 x 128] * [128 x 16]; wave wv owns rows wv*16..+15
    const int row2 = wv * 16 + lr;
    f32x4 acc2 = {};
    #pragma unroll
    for (int ks = 0; ks < 4; ++ks) {
        bf16x8 bvv = *(const bf16x8*)(W2t + (((size_t)t * 16 + lr) << 7) + ks * 32 + lg * 8);
        bf16x8 avv = *(const bf16x8*)((const char*)hl + row2 * 256 +
                         (((ks * 4 + lg) ^ (row2 & 7)) << 4));
        acc2 = __builtin_amdgcn_mfma_f32_16x16x32_bf16(avv, bvv, acc2, 0, 0, 0);
    }
    if (lr < NCLS) {
        const float b2v = b2[t * NCLS + lr];
        #pragma unroll
        for (int q = 0; q < 4; ++q) {
            const int row = wv * 16 + lg * 4 + q;
            if (row < m) out[(size_t)ridx[row] * NCLS + lr] = acc2[q] + b2v;
        }
    }
}

extern "C" void kernel_launch(void* const* d_in, const int* in_sizes, int n_in,
                              void* d_out, int out_size, void* d_ws, size_t ws_size,
                              hipStream_t stream) {
    (void)in_sizes; (void)n_in; (void)out_size; (void)ws_size;
    const float* x       = (const float*)d_in[0];
    const int*   task_id = (const int*)d_in[1];
    const float* W1      = (const float*)d_in[2];
    const float* b1      = (const float*)d_in[3];
    const float* W2      = (const float*)d_in[4];
    const float* b2      = (const float*)d_in[5];
    float* out = (float*)d_out;
    int* ws = (int*)d_ws;
    hipMemsetAsync(ws, 0, 64, stream);                 // zero cursors
    k_prep<<<784, 256, 0, stream>>>(task_id, W1, W2, ws);
    k_main<<<NTILES, 512, 0, stream>>>(x, b1, b2, ws, out);
}